// Round 1
// baseline (1057.668 us; speedup 1.0000x reference)
//
#include <hip/hip_runtime.h>
#include <hip/hip_bf16.h>
#include <math.h>

// Transformer block on gfx950. bf16 MFMA GEMMs (16x16x32), fp32 accumulate.
// Round-5: 256x256-tile 8-phase schedule (T3+T4 counted vmcnt + T5 setprio)
// for qkv/cproj/fc/mproj; 8 waves, BK=64, 128 KiB dbuf LDS, raw s_barrier
// (no vmcnt(0) drain in main loop). Conflict-free per-row chunk rotation
// carried over (SQ_LDS_BANK_CONFLICT was 0). sco/pv stay on the 128^2 body.

#define BM 128
#define BN 128
#define BK 64

typedef __attribute__((ext_vector_type(8))) short bf16x8;
typedef __attribute__((ext_vector_type(4))) float floatx4;

__device__ __forceinline__ short f2b(float f) {
  __hip_bfloat16 h = __float2bfloat16(f);
  return *reinterpret_cast<short*>(&h);
}
__device__ __forceinline__ float b2f(short s) {
  unsigned u = ((unsigned)(unsigned short)s) << 16;
  return __uint_as_float(u);
}

#if defined(__has_builtin)
#if __has_builtin(__builtin_amdgcn_global_load_lds)
#define HAS_GLLD 1
#endif
#endif

#ifdef HAS_GLLD
__device__ __forceinline__ void lds_dma16(const short* g, short* l) {
  __builtin_amdgcn_global_load_lds(
      (const __attribute__((address_space(1))) void*)g,
      (__attribute__((address_space(3))) void*)l, 16, 0, 0);
}
#endif

struct GP {
  const short* A; const short* B;
  long a_bs, b_bs;
  int lda, ldb;
  int a_kh; long a_hs;          // if a_kh>0: A addr = (k/a_kh)*a_hs + row*lda + k%a_kh
  const float* bias0; const float* bias1; const float* bias2;
  short* C0; short* C1; short* C2;
  float* Cf;
  int ldc, zmod;
  long cz0, cz1, c_zs;
  int K, kchunk;                // kchunk>0: this z handles K range [z*kchunk, +kchunk)
  float alpha;
  int zoff;
};

// ======================= old 128x128 2-barrier body (sco/pv) =======================
template<int MODE, int CAUSAL>
__device__ __forceinline__ void gemm_body(const GP& p)
{
  int bx = blockIdx.x;
  if (CAUSAL == 2) bx = gridDim.x - 1 - bx;   // longest K first
  const int m0 = bx * BM, n0 = blockIdx.y * BN;
  if (CAUSAL == 1 && n0 > m0 + (BM - 1)) return;
  const int z = blockIdx.z;
  const short* Ab = p.A + (size_t)z * p.a_bs;
  const short* Bb = p.B + (size_t)z * p.b_bs;
  int kbeg = 0, kend = p.K;
  if (p.kchunk) { kbeg = z * p.kchunk; kend = kbeg + p.kchunk; }
  if (CAUSAL == 2) { int lim = m0 + BM; if (lim < kend) kend = lim; }

  __shared__ __align__(16) short As[BM * BK];
  __shared__ __align__(16) short Bs[BN * BK];

  const int tid = threadIdx.x;
  const int lane = tid & 63, wave = tid >> 6;
  const int wm = (wave >> 1) * 64, wn = (wave & 1) * 64;
  const int l15 = lane & 15, quad = lane >> 4;
  const int rl = lane >> 3, pl = lane & 7;

  floatx4 acc[4][4];
#pragma unroll
  for (int i = 0; i < 4; i++)
#pragma unroll
    for (int j = 0; j < 4; j++) acc[i][j] = (floatx4){0.f, 0.f, 0.f, 0.f};

  const int cs = (pl - rl) & 7;

  for (int k0 = kbeg; k0 < kend; k0 += BK) {
    const short* Ak = Ab; int kb = k0;
    if (p.a_kh) { int h = k0 / p.a_kh; Ak = Ab + (size_t)h * p.a_hs; kb = k0 - h * p.a_kh; }
#pragma unroll
    for (int s = 0; s < 4; s++) {
      const int win = wave * 4 + s;
      const int row = win * 8 + rl;
      const short* ga = Ak + (size_t)(m0 + row) * p.lda + kb + cs * 8;
      const short* gb = Bb + (size_t)(n0 + row) * p.ldb + k0 + cs * 8;
#ifdef HAS_GLLD
      lds_dma16(ga, &As[win * 512]);
      lds_dma16(gb, &Bs[win * 512]);
#else
      *(int4*)&As[win * 512 + lane * 8] = *(const int4*)ga;
      *(int4*)&Bs[win * 512 + lane * 8] = *(const int4*)gb;
#endif
    }
    __syncthreads();
#pragma unroll
    for (int t = 0; t < 2; t++) {
      bf16x8 fa[4], fb[4];
#pragma unroll
      for (int i = 0; i < 4; i++) {
        const int ra = wm + i * 16 + l15;
        fa[i] = *(const bf16x8*)&As[ra * 64 + (((t << 2) + quad + ra) & 7) * 8];
        const int rb = wn + i * 16 + l15;
        fb[i] = *(const bf16x8*)&Bs[rb * 64 + (((t << 2) + quad + rb) & 7) * 8];
      }
#pragma unroll
      for (int i = 0; i < 4; i++)
#pragma unroll
        for (int j = 0; j < 4; j++)
          acc[i][j] = __builtin_amdgcn_mfma_f32_16x16x32_bf16(fa[i], fb[j], acc[i][j], 0, 0, 0);
    }
    __syncthreads();
  }

  const long coff = (long)(z % p.zmod) * p.cz0 + (long)(z / p.zmod) * p.cz1;
#pragma unroll
  for (int j = 0; j < 4; j++) {
    const int col = n0 + wn + j * 16 + l15;
    if constexpr (MODE == 0) {
#pragma unroll
      for (int i = 0; i < 4; i++) {
        const int rb = m0 + wm + i * 16 + quad * 4;
#pragma unroll
        for (int r = 0; r < 4; r++)
          p.C0[coff + (size_t)(rb + r) * p.ldc + col] = f2b(acc[i][j][r] * p.alpha);
      }
    }
  }
}

// ======================= new 256x256 8-phase body =======================
#define BARX asm volatile("s_barrier" ::: "memory")
#define VMC4 asm volatile("s_waitcnt vmcnt(4)" ::: "memory")
#define VMC0 asm volatile("s_waitcnt vmcnt(0)" ::: "memory")

#define LDA_(D, MH) do { \
  _Pragma("unroll") for (int i_ = 0; i_ < 4; i_++) { \
    const int ra_ = wm + (MH) * 64 + i_ * 16 + l15; \
    a[i_][0] = rdA(D, ra_, 0); a[i_][1] = rdA(D, ra_, 1); } } while (0)

#define LDB_(D, NH, BV) do { \
  _Pragma("unroll") for (int j_ = 0; j_ < 2; j_++) { \
    const int rb_ = wn + (NH) * 32 + j_ * 16 + l15; \
    BV[j_][0] = rdB(D, rb_, 0); BV[j_][1] = rdB(D, rb_, 1); } } while (0)

#define MMA_(MI0, NJ0, BV) do { \
  __builtin_amdgcn_s_setprio(1); \
  _Pragma("unroll") for (int i_ = 0; i_ < 4; i_++) \
  _Pragma("unroll") for (int j_ = 0; j_ < 2; j_++) \
  _Pragma("unroll") for (int t_ = 0; t_ < 2; t_++) \
    acc[(MI0) + i_][(NJ0) + j_] = __builtin_amdgcn_mfma_f32_16x16x32_bf16( \
        a[i_][t_], BV[j_][t_], acc[(MI0) + i_][(NJ0) + j_], 0, 0, 0); \
  __builtin_amdgcn_s_setprio(0); } while (0)

// LDS (shorts): [A_d0 | B_d0 | A_d1 | B_d1], each 16384 (256 rows x 64).
// Region halves (128 rows = 16 KB) are the staging unit: 8 waves x 2 issues x 1 KB.
// Per-row chunk rotation: chunk c of row r lands at slot (c + r) & 7 -> 0 conflicts.
//
// 8-phase stage map (iter i, tiles 2i [d0], 2i+1 [d1]), FIFO-verified:
//   ph1: A d1 h0 <- t(2i+1)   ph5: A d0 h0 <- t(2i+2)
//   ph2: A d1 h1 <- t(2i+1)   ph6: A d0 h1 <- t(2i+2)
//   ph3: B d0 h0 <- t(2i+2)   ph7: B d1 h0 <- t(2i+3)
//   ph4: B d0 h1 <- t(2i+2)   ph8: B d1 h1 <- t(2i+3)
// vmcnt(4) at ph4/ph8 drains 8 oldest of 12 outstanding -> exactly the
// half-tiles needed by the next 4 phases. Last iter: ph4 vmcnt(0), no stages.
template<int MODE, int CAUSAL>
__device__ __forceinline__ void gemm256_body(const GP& p)
{
  extern __shared__ __align__(16) short lds[];
  int bx = blockIdx.x;
  if (CAUSAL == 2) bx = gridDim.x - 1 - bx;
  const int m0 = bx * 256, n0 = blockIdx.y * 256;
  if (CAUSAL == 1 && n0 > m0 + 255) return;
  const int z = blockIdx.z;
  const short* Ab = p.A + (size_t)z * p.a_bs;
  const short* Bb = p.B + (size_t)z * p.b_bs;
  int kbeg = 0, kend = p.K;
  if (p.kchunk) { kbeg = z * p.kchunk; kend = kbeg + p.kchunk; }
  if (CAUSAL == 2) { int lim = m0 + 256; if (lim < kend) kend = lim; }
  const int NI = (kend - kbeg) >> 7;          // iterations of 2 K-tiles (BK=64)

  const int tid = threadIdx.x;
  const int lane = tid & 63, wave = tid >> 6;
  const int wm = (wave >> 2) * 128, wn = (wave & 3) * 64;
  const int l15 = lane & 15, quad = lane >> 4;
  const int rl = lane >> 3, pl = lane & 7;
  const int cs = (pl - rl) & 7;

  const size_t a8 = (size_t)p.lda * 8, a128 = (size_t)p.lda * 128;
  const size_t b8 = (size_t)p.ldb * 8, b128 = (size_t)p.ldb * 128;
  const size_t aRow = (size_t)(m0 + wave * 16 + rl) * p.lda + cs * 8;
  const size_t bRow = (size_t)(n0 + wave * 16 + rl) * p.ldb + cs * 8;
  const int ldsW = wave * 1024;

  auto stageA = [&](int kt, int h) {
    const int k0 = kbeg + (kt << 6);
    const short* Ak = Ab; int kb = k0;
    if (p.a_kh) { const int hh = k0 / p.a_kh; Ak += (size_t)hh * p.a_hs; kb -= hh * p.a_kh; }
    const int lb = ((kt & 1) << 15) + (h << 13) + ldsW;
    const short* g0 = Ak + aRow + (h ? a128 : 0) + kb;
#ifdef HAS_GLLD
    lds_dma16(g0, &lds[lb]);
    lds_dma16(g0 + a8, &lds[lb + 512]);
#else
    *(int4*)&lds[lb + lane * 8] = *(const int4*)g0;
    *(int4*)&lds[lb + 512 + lane * 8] = *(const int4*)(g0 + a8);
#endif
  };
  auto stageB = [&](int kt, int h) {
    const int k0 = kbeg + (kt << 6);
    const int lb = ((kt & 1) << 15) + 16384 + (h << 13) + ldsW;
    const short* g0 = Bb + bRow + (h ? b128 : 0) + k0;
#ifdef HAS_GLLD
    lds_dma16(g0, &lds[lb]);
    lds_dma16(g0 + b8, &lds[lb + 512]);
#else
    *(int4*)&lds[lb + lane * 8] = *(const int4*)g0;
    *(int4*)&lds[lb + 512 + lane * 8] = *(const int4*)(g0 + b8);
#endif
  };
  auto rdA = [&](int d, int ra, int t) {
    return *(const bf16x8*)&lds[(d << 15) + ra * 64 + ((((t << 2) + quad + ra) & 7) << 3)];
  };
  auto rdB = [&](int d, int rb, int t) {
    return *(const bf16x8*)&lds[(d << 15) + 16384 + rb * 64 + ((((t << 2) + quad + rb) & 7) << 3)];
  };

  floatx4 acc[8][4];
#pragma unroll
  for (int i = 0; i < 8; i++)
#pragma unroll
    for (int j = 0; j < 4; j++) acc[i][j] = (floatx4){0.f, 0.f, 0.f, 0.f};

  bf16x8 a[4][2], b0[2][2], b1[2][2];

  // prologue: tile0 A+B and tile1 B. vmcnt(4) -> tile0 landed, tile1-B in flight.
  stageA(0, 0); stageA(0, 1); stageB(0, 0); stageB(0, 1); stageB(1, 0); stageB(1, 1);
  VMC4;
  BARX;

  for (int it = 0; it < NI; ++it) {
    const bool full = (it < NI - 1);
    const int t1 = 2 * it + 1;
    // phase 1: even tile, quadrant (m0,n0)
    LDA_(0, 0); LDB_(0, 0, b0);
    stageA(t1, 0);
    BARX;
    MMA_(0, 0, b0);
    BARX;
    // phase 2: (m0,n1)
    LDB_(0, 1, b1);
    stageA(t1, 1);
    BARX;
    MMA_(0, 2, b1);
    BARX;
    // phase 3: (m1,n1)
    LDA_(0, 1);
    if (full) stageB(t1 + 1, 0);
    BARX;
    MMA_(4, 2, b1);
    BARX;
    // phase 4: (m1,n0) — reuses a (m1) and b0
    if (full) stageB(t1 + 1, 1);
    BARX;
    MMA_(4, 0, b0);
    if (full) { VMC4; } else { VMC0; }
    BARX;
    // phase 5: odd tile, (m0,n0)
    LDA_(1, 0); LDB_(1, 0, b0);
    if (full) stageA(t1 + 1, 0);
    BARX;
    MMA_(0, 0, b0);
    BARX;
    // phase 6: (m0,n1)
    LDB_(1, 1, b1);
    if (full) stageA(t1 + 1, 1);
    BARX;
    MMA_(0, 2, b1);
    BARX;
    // phase 7: (m1,n1)
    LDA_(1, 1);
    if (full) stageB(t1 + 2, 0);
    BARX;
    MMA_(4, 2, b1);
    BARX;
    // phase 8: (m1,n0)
    if (full) stageB(t1 + 2, 1);
    BARX;
    MMA_(4, 0, b0);
    if (full) VMC4;
    BARX;
  }

  // C/D layout (m89): col = lane&15, row = quad*4 + reg
  const long coff = (long)(z % p.zmod) * p.cz0 + (long)(z / p.zmod) * p.cz1;
#pragma unroll
  for (int nj = 0; nj < 4; nj++) {
    const int col = n0 + wn + nj * 16 + l15;
    if constexpr (MODE == 0) {
#pragma unroll
      for (int mi = 0; mi < 8; mi++) {
        const int rb = m0 + wm + mi * 16 + quad * 4;
#pragma unroll
        for (int r = 0; r < 4; r++)
          p.C0[coff + (size_t)(rb + r) * p.ldc + col] = f2b(acc[mi][nj][r] * p.alpha);
      }
    } else if constexpr (MODE == 5) {
      const int part = (n0 + wn) / 768;        // block-uniform: 0=q, 1=k, 2=v
      const int cc = col - part * 768;
      const float* bp_ = (part == 0) ? p.bias0 : ((part == 1) ? p.bias1 : p.bias2);
      const float bvv = bp_[(p.zoff + z) * 768 + cc];
      if (part < 2) {
        short* dst = part ? p.C1 : p.C0;
#pragma unroll
        for (int mi = 0; mi < 8; mi++) {
          const int rb = m0 + wm + mi * 16 + quad * 4;
#pragma unroll
          for (int r = 0; r < 4; r++)
            dst[(size_t)z * p.c_zs + (size_t)(rb + r) * 768 + cc] = f2b(acc[mi][nj][r] + bvv);
        }
      } else {
#pragma unroll
        for (int mi = 0; mi < 8; mi++) {
          const int rb = m0 + wm + mi * 16 + quad * 4;
          short4 pk;
          pk.x = f2b(acc[mi][nj][0] + bvv);
          pk.y = f2b(acc[mi][nj][1] + bvv);
          pk.z = f2b(acc[mi][nj][2] + bvv);
          pk.w = f2b(acc[mi][nj][3] + bvv);
          const size_t addr = (((size_t)z * 4 + (rb >> 10)) * 768 + cc) * 1024 + (rb & 1023);
          *(short4*)&p.C2[addr] = pk;
        }
      }
    } else if constexpr (MODE == 4) {
#pragma unroll
      for (int mi = 0; mi < 8; mi++) {
        const int rb = m0 + wm + mi * 16 + quad * 4;
#pragma unroll
        for (int r = 0; r < 4; r++)
          p.Cf[(size_t)z * p.c_zs + (size_t)(rb + r) * p.ldc + col] = acc[mi][nj][r];
      }
    } else {  // MODE 3: exact gelu
      const float bvv = p.bias0[col];
#pragma unroll
      for (int mi = 0; mi < 8; mi++) {
        const int rb = m0 + wm + mi * 16 + quad * 4;
#pragma unroll
        for (int r = 0; r < 4; r++) {
          float t = acc[mi][nj][r] + bvv;
          p.C0[(size_t)(rb + r) * p.ldc + col] = f2b(0.5f * t * (1.0f + erff(t * 0.70710678118654752440f)));
        }
      }
    }
  }
}

__global__ void __launch_bounds__(512) gemm_qkv(GP p)   { gemm256_body<5, 0>(p); }
__global__ void __launch_bounds__(256) gemm_sco(GP p)   { gemm_body<0, 1>(p); }
__global__ void __launch_bounds__(256) gemm_pv(GP p)    { gemm_body<0, 2>(p); }
__global__ void __launch_bounds__(512) gemm_cproj(GP p) { gemm256_body<4, 0>(p); }
__global__ void __launch_bounds__(512) gemm_fc(GP p)    { gemm256_body<3, 0>(p); }
__global__ void __launch_bounds__(512) gemm_mproj(GP p) { gemm256_body<4, 0>(p); }

__global__ void __launch_bounds__(256) ln_kernel(
    const float* __restrict__ in, const float* __restrict__ g, const float* __restrict__ b,
    float* __restrict__ outf, short* __restrict__ outb)
{
  const long r = blockIdx.x;
  const float* x = in + r * 768;
  const int tid = threadIdx.x;
  float v0 = x[tid], v1 = x[tid + 256], v2 = x[tid + 512];
  float s = v0 + v1 + v2;
  float sq = v0 * v0 + v1 * v1 + v2 * v2;
  __shared__ float red[8];
  int lane = tid & 63, wave = tid >> 6;
#pragma unroll
  for (int o = 1; o < 64; o <<= 1) { s += __shfl_xor(s, o); sq += __shfl_xor(sq, o); }
  if (lane == 0) { red[wave] = s; red[4 + wave] = sq; }
  __syncthreads();
  s = red[0] + red[1] + red[2] + red[3];
  sq = red[4] + red[5] + red[6] + red[7];
  float mean = s * (1.0f / 768.0f);
  float var = sq * (1.0f / 768.0f) - mean * mean;
  float inv = rsqrtf(var + 1e-5f);
#pragma unroll
  for (int u = 0; u < 3; u++) {
    int c = tid + u * 256;
    float v = (u == 0) ? v0 : ((u == 1) ? v1 : v2);
    float y = (v - mean) * inv * g[c] + b[c];
    outf[r * 768 + c] = y;
    outb[r * 768 + c] = f2b(y);
  }
}

__global__ void __launch_bounds__(256) reduce_ln_kernel(
    const float* __restrict__ part, long pzs, int nsplit,
    const float* __restrict__ bias, const float* __restrict__ resid,
    const float* __restrict__ g, const float* __restrict__ b,
    float* __restrict__ outf, short* __restrict__ outb)
{
  const long r = blockIdx.x;
  const int tid = threadIdx.x;
  float y[3];
#pragma unroll
  for (int u = 0; u < 3; u++) {
    const int c = tid + u * 256;
    const size_t idx = (size_t)r * 768 + c;
    float s = part[idx];
    for (int zz = 1; zz < nsplit; zz++) s += part[(size_t)zz * pzs + idx];
    y[u] = s + bias[c] + resid[idx];
  }
  float s = y[0] + y[1] + y[2];
  float sq = y[0] * y[0] + y[1] * y[1] + y[2] * y[2];
  __shared__ float red[8];
  int lane = tid & 63, wave = tid >> 6;
#pragma unroll
  for (int o = 1; o < 64; o <<= 1) { s += __shfl_xor(s, o); sq += __shfl_xor(sq, o); }
  if (lane == 0) { red[wave] = s; red[4 + wave] = sq; }
  __syncthreads();
  s = red[0] + red[1] + red[2] + red[3];
  sq = red[4] + red[5] + red[6] + red[7];
  float mean = s * (1.0f / 768.0f);
  float var = sq * (1.0f / 768.0f) - mean * mean;
  float inv = rsqrtf(var + 1e-5f);
#pragma unroll
  for (int u = 0; u < 3; u++) {
    const int c = tid + u * 256;
    const float v = (y[u] - mean) * inv * g[c] + b[c];
    outf[(size_t)r * 768 + c] = v;
    outb[(size_t)r * 768 + c] = f2b(v);
  }
}

__global__ void __launch_bounds__(256) softmax_kernel(short* __restrict__ sc)
{
  const long gr = blockIdx.x;
  const int i = (int)(gr & 1023);
  short* row = sc + (gr >> 10) * (1024L * 1024) + (long)i * 1024;
  const int L = i + 1;
  const int tid = threadIdx.x;
  const int lane = tid & 63, wave = tid >> 6;
  __shared__ float red[4];
  float v[4];
  float mx = -3.0e38f;
#pragma unroll
  for (int s = 0; s < 4; s++) {
    int j = tid + s * 256;
    v[s] = (j < L) ? b2f(row[j]) : -3.0e38f;
    mx = fmaxf(mx, v[s]);
  }
#pragma unroll
  for (int o = 1; o < 64; o <<= 1) mx = fmaxf(mx, __shfl_xor(mx, o));
  if (lane == 0) red[wave] = mx;
  __syncthreads();
  mx = fmaxf(fmaxf(red[0], red[1]), fmaxf(red[2], red[3]));
  __syncthreads();
  float sum = 0.0f;
#pragma unroll
  for (int s = 0; s < 4; s++) {
    int j = tid + s * 256;
    if (j < L) { v[s] = __expf(v[s] - mx); sum += v[s]; }
  }
#pragma unroll
  for (int o = 1; o < 64; o <<= 1) sum += __shfl_xor(sum, o);
  if (lane == 0) red[wave] = sum;
  __syncthreads();
  sum = red[0] + red[1] + red[2] + red[3];
  float inv = 1.0f / sum;
#pragma unroll
  for (int s = 0; s < 4; s++) {
    int j = tid + s * 256;
    if (j < L) row[j] = f2b(v[s] * inv);
  }
  const int hi = i | 127;
  for (int j = L + tid; j <= hi; j += 256) row[j] = 0;
}

__global__ void __launch_bounds__(256) reduce_kernel(
    const float* __restrict__ part, long pzs, int nsplit,
    const float* __restrict__ bias, const float* __restrict__ resid,
    float* __restrict__ out)
{
  const size_t idx = ((size_t)blockIdx.x * 256 + threadIdx.x) * 4;
  float4 s = *(const float4*)&part[idx];
  for (int zz = 1; zz < nsplit; zz++) {
    float4 q = *(const float4*)&part[(size_t)zz * pzs + idx];
    s.x += q.x; s.y += q.y; s.z += q.z; s.w += q.w;
  }
  const int c = (int)(idx % 768);
  float4 b = *(const float4*)&bias[c];
  float4 r = *(const float4*)&resid[idx];
  *(float4*)&out[idx] = make_float4(s.x + b.x + r.x, s.y + b.y + r.y,
                                    s.z + b.z + r.z, s.w + b.w + r.w);
}

// W[R][C] fp32 -> Wt[C][R] bf16, per-z src/dst strides
__global__ void __launch_bounds__(256) transpose_kernel(
    const float* __restrict__ W, short* __restrict__ Wt, int R, int C, long szs, long dzs)
{
  __shared__ float tile[32][33];
  const int c0 = blockIdx.x * 32, r0 = blockIdx.y * 32;
  const float* Wz = W + (size_t)blockIdx.z * szs;
  short* Wtz = Wt + (size_t)blockIdx.z * dzs;
  const int tx = threadIdx.x, ty = threadIdx.y;
#pragma unroll
  for (int i = 0; i < 32; i += 8)
    tile[ty + i][tx] = Wz[(size_t)(r0 + ty + i) * C + (c0 + tx)];
  __syncthreads();
#pragma unroll
  for (int i = 0; i < 32; i += 8)
    Wtz[(size_t)(c0 + ty + i) * R + (r0 + tx)] = f2b(tile[tx][ty + i]);
}

extern "C" void kernel_launch(void* const* d_in, const int* in_sizes, int n_in,
                              void* d_out, int out_size, void* d_ws, size_t ws_size,
                              hipStream_t stream)
{
  (void)in_sizes; (void)n_in; (void)out_size;
  const float* inputs = (const float*)d_in[0];
  const float* g1  = (const float*)d_in[1];
  const float* b1  = (const float*)d_in[2];
  const float* Wq  = (const float*)d_in[3];
  const float* bq  = (const float*)d_in[4];
  const float* Wk  = (const float*)d_in[5];
  const float* bk  = (const float*)d_in[6];
  const float* Wv  = (const float*)d_in[7];
  const float* bv  = (const float*)d_in[8];
  const float* Wc  = (const float*)d_in[9];
  const float* bc  = (const float*)d_in[10];
  const float* g2  = (const float*)d_in[11];
  const float* b2  = (const float*)d_in[12];
  const float* Wfc = (const float*)d_in[13];
  const float* bfc = (const float*)d_in[14];
  const float* Wp  = (const float*)d_in[15];
  const float* bp  = (const float*)d_in[16];
  float* out = (float*)d_out;

  const size_t NS = 4096, E = 768, S = 1024;

  // 128 KiB dynamic LDS for the 8-phase kernels
  hipFuncSetAttribute((const void*)gemm_qkv,   hipFuncAttributeMaxDynamicSharedMemorySize, 131072);
  hipFuncSetAttribute((const void*)gemm_cproj, hipFuncAttributeMaxDynamicSharedMemorySize, 131072);
  hipFuncSetAttribute((const void*)gemm_fc,    hipFuncAttributeMaxDynamicSharedMemorySize, 131072);
  hipFuncSetAttribute((const void*)gemm_mproj, hipFuncAttributeMaxDynamicSharedMemorySize, 131072);

  char* base = (char*)d_ws;
  size_t off = 0;
  auto alloc = [&](size_t n) { char* r = base + off; off = (off + n + 255) & ~(size_t)255; return r; };

  // ---- persistent region (live across whole launch) ----
  float* x_f  = (float*)alloc(NS * E * 4);
  short* x_b  = (short*)alloc(NS * E * 2);
  short* Wqkv = (short*)alloc(12 * 3 * E * E * 2);   // [h][{q,k,v}][768][768] bf16 (B^T)
  short* WcT  = (short*)alloc(E * 9216 * 2);
  short* WfcT = (short*)alloc(3072 * E * 2);
  short* WpT  = (short*)alloc(E * 3072 * 2);
  short* cat  = (short*)alloc(12 * NS * E * 2);      // head-major [h][4096][768]; aliases partB later

  // ---- overlay region R: attention pool, then post-attention buffers ----
  char* Rp = base + off;
  const size_t R_size = (ws_size > off) ? (ws_size - off) : 0;

  const size_t per_h = 3 * (NS * E * 2) + 4 * S * S * 2;
  static const int Gs[5] = {6, 4, 3, 2, 1};
  int G = 1;
  for (int i = 0; i < 5; i++)
    if ((size_t)Gs[i] * per_h <= R_size) { G = Gs[i]; break; }

  short* q_g  = (short*)Rp;
  short* k_g  = q_g + (size_t)G * NS * E;
  short* vT_g = k_g + (size_t)G * NS * E;            // [z*4+n][768][1024]
  short* sc_g = vT_g + (size_t)G * NS * E;           // [z*4+n][1024][1024]

  // post-attention overlay (attention pool dead by then)
  size_t o2 = 0;
  float* partA = (float*)(Rp + o2); o2 += 4 * NS * E * 4;   // c_proj split-K=4 partials
  float* y2_f  = (float*)(Rp + o2); o2 += NS * E * 4;
  short* y2_b  = (short*)(Rp + o2); o2 += NS * E * 2;
  short* h_b   = (short*)(Rp + o2); o2 += NS * 3072 * 2;
  float* partB = (float*)cat;                               // 50.3 MB <= cat (75.5 MB)

  const dim3 tb(32, 8);
  transpose_kernel<<<dim3(24, 24, 12), tb, 0, stream>>>(Wq, Wqkv,         768, 768, (long)(E*E), (long)(3*E*E));
  transpose_kernel<<<dim3(24, 24, 12), tb, 0, stream>>>(Wk, Wqkv + E*E,   768, 768, (long)(E*E), (long)(3*E*E));
  transpose_kernel<<<dim3(24, 24, 12), tb, 0, stream>>>(Wv, Wqkv + 2*E*E, 768, 768, (long)(E*E), (long)(3*E*E));
  transpose_kernel<<<dim3(24, 288, 1), tb, 0, stream>>>(Wc, WcT, 9216, 768, 0, 0);
  transpose_kernel<<<dim3(96, 24, 1),  tb, 0, stream>>>(Wfc, WfcT, 768, 3072, 0, 0);
  transpose_kernel<<<dim3(24, 96, 1),  tb, 0, stream>>>(Wp, WpT, 3072, 768, 0, 0);

  ln_kernel<<<4096, 256, 0, stream>>>(inputs, g1, b1, x_f, x_b);

  const float sca = 0.03608439182435161f;  // 1/sqrt(768)
  for (int h0 = 0; h0 < 12; h0 += G) {
    {  // merged QKV: N = 2304 per head, 256^2 8-phase
      GP p{};
      p.A = x_b; p.lda = 768; p.a_bs = 0;
      p.B = Wqkv + (size_t)h0 * 3 * E * E; p.ldb = 768; p.b_bs = (long)(3 * E * E);
      p.bias0 = bq; p.bias1 = bk; p.bias2 = bv; p.zoff = h0;
      p.C0 = q_g; p.C1 = k_g; p.C2 = vT_g; p.c_zs = (long)(NS * E);
      p.ldc = 768; p.zmod = 1;
      p.K = 768; p.alpha = 1.0f;
      gemm_qkv<<<dim3(16, 9, G), 512, 131072, stream>>>(p);
    }
    {  // scores = q k^T / sqrt(E)  (128^2 body, unchanged)
      GP p{};
      p.A = q_g; p.lda = 768; p.a_bs = (long)(S * E);
      p.B = k_g; p.ldb = 768; p.b_bs = (long)(S * E);
      p.C0 = sc_g; p.ldc = 1024; p.zmod = 1; p.cz0 = 0; p.cz1 = (long)(S * S);
      p.K = 768; p.alpha = sca;
      gemm_sco<<<dim3(8, 8, 4 * G), 256, 0, stream>>>(p);
    }
    softmax_kernel<<<4 * G * 1024, 256, 0, stream>>>(sc_g);
    {  // heads = attn @ v -> cat[h][4096][768]  (128^2 body, unchanged)
      GP p{};
      p.A = sc_g; p.lda = 1024; p.a_bs = (long)(S * S);
      p.B = vT_g; p.ldb = 1024; p.b_bs = (long)(E * S);
      p.C0 = cat + (size_t)h0 * NS * E; p.ldc = 768;
      p.zmod = 4; p.cz0 = (long)(S * E); p.cz1 = (long)(NS * E);
      p.K = 1024; p.alpha = 1.0f;
      gemm_pv<<<dim3(8, 6, 4 * G), 256, 0, stream>>>(p);
    }
  }

  {  // c_proj split-K=4 (kchunk = 2304 = 3 heads) over head-major cat
    GP p{};
    p.A = cat; p.lda = 768; p.a_kh = 768; p.a_hs = (long)(NS * E);
    p.B = WcT; p.ldb = 9216;
    p.Cf = partA; p.ldc = 768; p.c_zs = (long)(NS * E); p.zmod = 1;
    p.K = 9216; p.kchunk = 2304; p.alpha = 1.0f;
    gemm_cproj<<<dim3(16, 3, 4), 512, 131072, stream>>>(p);
  }
  // y = sum(partA) + bc + x_f; y2 = LN(y)  (fused; y never materialized)
  reduce_ln_kernel<<<4096, 256, 0, stream>>>(partA, (long)(NS * E), 4, bc, x_f,
                                             g2, b2, y2_f, y2_b);

  {  // fc + exact gelu
    GP p{};
    p.A = y2_b; p.lda = 768;
    p.B = WfcT; p.ldb = 768;
    p.bias0 = bfc; p.C0 = h_b; p.ldc = 3072; p.zmod = 1;
    p.K = 768; p.alpha = 1.0f;
    gemm_fc<<<dim3(16, 12, 1), 512, 131072, stream>>>(p);
  }
  {  // proj split-K=4
    GP p{};
    p.A = h_b; p.lda = 3072;
    p.B = WpT; p.ldb = 3072;
    p.Cf = partB; p.ldc = 768; p.c_zs = (long)(NS * E); p.zmod = 1;
    p.K = 3072; p.kchunk = 768; p.alpha = 1.0f;
    gemm_mproj<<<dim3(16, 3, 4), 512, 131072, stream>>>(p);
  }
  reduce_kernel<<<3072, 256, 0, stream>>>(partB, (long)(NS * E), 4, bp, y2_f, out);
}

// Round 2
// 985.553 us; speedup vs baseline: 1.0732x; 1.0732x over previous
//
#include <hip/hip_runtime.h>
#include <hip/hip_bf16.h>
#include <math.h>

// Transformer block on gfx950. bf16 MFMA GEMMs (16x16x32), fp32 accumulate.
// Round-6: REVERT to the verified 128^2 2-barrier body for all GEMMs (the
// 8-phase port hit the documented m232 failure mode: refcheck OK, overlap not
// reproduced, 1-block/CU occupancy loss). One change vs the 971/993us base:
// MODE-3 GELU now uses the tanh/sigmoid form (1 v_exp + fast divide) instead
// of libm erff — round-1 isolated fc's erff epilogue as the fc bottleneck
// (cproj same loop ~500 TF, fc 164 TF; only difference = epilogue).

#define BM 128
#define BN 128
#define BK 64

typedef __attribute__((ext_vector_type(8))) short bf16x8;
typedef __attribute__((ext_vector_type(4))) float floatx4;

__device__ __forceinline__ short f2b(float f) {
  __hip_bfloat16 h = __float2bfloat16(f);
  return *reinterpret_cast<short*>(&h);
}
__device__ __forceinline__ float b2f(short s) {
  unsigned u = ((unsigned)(unsigned short)s) << 16;
  return __uint_as_float(u);
}

#if defined(__has_builtin)
#if __has_builtin(__builtin_amdgcn_global_load_lds)
#define HAS_GLLD 1
#endif
#endif

#ifdef HAS_GLLD
__device__ __forceinline__ void lds_dma16(const short* g, short* l) {
  __builtin_amdgcn_global_load_lds(
      (const __attribute__((address_space(1))) void*)g,
      (__attribute__((address_space(3))) void*)l, 16, 0, 0);
}
#endif

struct GP {
  const short* A; const short* B;
  long a_bs, b_bs;
  int lda, ldb;
  int a_kh; long a_hs;          // if a_kh>0: A addr = (k/a_kh)*a_hs + row*lda + k%a_kh
  const float* bias0; const float* bias1; const float* bias2;
  short* C0; short* C1; short* C2;
  float* Cf;
  int ldc, zmod;
  long cz0, cz1, c_zs;
  int K, kchunk;                // kchunk>0: this z handles K range [z*kchunk, +kchunk)
  float alpha;
  int zoff;
};

// MODE 0: C0 = bf16(acc*alpha)            (CAUSAL=1 tile-skip; CAUSAL=2 K-limit)
// MODE 3: C0 = bf16(gelu(acc + bias0[col]))   [tanh-form gelu]
// MODE 4: Cf[z*c_zs + ...] = acc          (split-K fp32 partial)
// MODE 5: QKV routing by column part: q->C0, k->C1, v->C2 (transposed layout)
template<int MODE, int CAUSAL>
__device__ __forceinline__ void gemm_body(const GP& p)
{
  int bx = blockIdx.x;
  if (CAUSAL == 2) bx = gridDim.x - 1 - bx;   // longest K first
  const int m0 = bx * BM, n0 = blockIdx.y * BN;
  if (CAUSAL == 1 && n0 > m0 + (BM - 1)) return;
  const int z = blockIdx.z;
  const short* Ab = p.A + (size_t)z * p.a_bs;
  const short* Bb = p.B + (size_t)z * p.b_bs;
  int kbeg = 0, kend = p.K;
  if (p.kchunk) { kbeg = z * p.kchunk; kend = kbeg + p.kchunk; }
  if (CAUSAL == 2) { int lim = m0 + BM; if (lim < kend) kend = lim; }

  // Row = 128 B (8 chunks of 16 B); chunk c of row r stored at pos (c + r) & 7.
  // ds_read_b128: within a 16-lane quarter (fixed quad) rows cover each rotation
  // twice -> 2-way bank aliasing only (free, m136).
  __shared__ __align__(16) short As[BM * BK];
  __shared__ __align__(16) short Bs[BN * BK];

  const int tid = threadIdx.x;
  const int lane = tid & 63, wave = tid >> 6;
  const int wm = (wave >> 1) * 64, wn = (wave & 1) * 64;
  const int l15 = lane & 15, quad = lane >> 4;
  const int rl = lane >> 3, pl = lane & 7;    // 8 rows x 8 chunk-slots per window

  floatx4 acc[4][4];
#pragma unroll
  for (int i = 0; i < 4; i++)
#pragma unroll
    for (int j = 0; j < 4; j++) acc[i][j] = (floatx4){0.f, 0.f, 0.f, 0.f};

  const int cs = (pl - rl) & 7;               // global chunk landing at LDS pos pl

  for (int k0 = kbeg; k0 < kend; k0 += BK) {
    const short* Ak = Ab; int kb = k0;
    if (p.a_kh) { int h = k0 / p.a_kh; Ak = Ab + (size_t)h * p.a_hs; kb = k0 - h * p.a_kh; }
#pragma unroll
    for (int s = 0; s < 4; s++) {
      const int win = wave * 4 + s;           // 16 windows of 8 rows (1 KB each)
      const int row = win * 8 + rl;
      const short* ga = Ak + (size_t)(m0 + row) * p.lda + kb + cs * 8;
      const short* gb = Bb + (size_t)(n0 + row) * p.ldb + k0 + cs * 8;
#ifdef HAS_GLLD
      lds_dma16(ga, &As[win * 512]);
      lds_dma16(gb, &Bs[win * 512]);
#else
      *(int4*)&As[win * 512 + lane * 8] = *(const int4*)ga;
      *(int4*)&Bs[win * 512 + lane * 8] = *(const int4*)gb;
#endif
    }
    __syncthreads();
#pragma unroll
    for (int t = 0; t < 2; t++) {             // two 16x16x32 k-steps per BK=64 tile
      bf16x8 fa[4], fb[4];
#pragma unroll
      for (int i = 0; i < 4; i++) {
        const int ra = wm + i * 16 + l15;
        fa[i] = *(const bf16x8*)&As[ra * 64 + (((t << 2) + quad + ra) & 7) * 8];
        const int rb = wn + i * 16 + l15;
        fb[i] = *(const bf16x8*)&Bs[rb * 64 + (((t << 2) + quad + rb) & 7) * 8];
      }
#pragma unroll
      for (int i = 0; i < 4; i++)
#pragma unroll
        for (int j = 0; j < 4; j++)
          acc[i][j] = __builtin_amdgcn_mfma_f32_16x16x32_bf16(fa[i], fb[j], acc[i][j], 0, 0, 0);
    }
    __syncthreads();
  }

  // C/D layout (m89): col = lane&15, row = quad*4 + reg
  const long coff = (long)(z % p.zmod) * p.cz0 + (long)(z / p.zmod) * p.cz1;
#pragma unroll
  for (int j = 0; j < 4; j++) {
    const int col = n0 + wn + j * 16 + l15;
    if constexpr (MODE == 0) {
#pragma unroll
      for (int i = 0; i < 4; i++) {
        const int rb = m0 + wm + i * 16 + quad * 4;
#pragma unroll
        for (int r = 0; r < 4; r++)
          p.C0[coff + (size_t)(rb + r) * p.ldc + col] = f2b(acc[i][j][r] * p.alpha);
      }
    } else if constexpr (MODE == 5) {
      const int part = (n0 + wn) / 768;        // wave-uniform: 0=q, 1=k, 2=v
      const int cc = col - part * 768;
      const float* bp_ = (part == 0) ? p.bias0 : ((part == 1) ? p.bias1 : p.bias2);
      const float bvv = bp_[(p.zoff + z) * 768 + cc];
      if (part < 2) {
        short* dst = part ? p.C1 : p.C0;
#pragma unroll
        for (int i = 0; i < 4; i++) {
          const int rb = m0 + wm + i * 16 + quad * 4;
#pragma unroll
          for (int r = 0; r < 4; r++)
            dst[(size_t)z * p.c_zs + (size_t)(rb + r) * 768 + cc] = f2b(acc[i][j][r] + bvv);
        }
      } else {
#pragma unroll
        for (int i = 0; i < 4; i++) {
          const int rb = m0 + wm + i * 16 + quad * 4;
          short4 pk;
          pk.x = f2b(acc[i][j][0] + bvv);
          pk.y = f2b(acc[i][j][1] + bvv);
          pk.z = f2b(acc[i][j][2] + bvv);
          pk.w = f2b(acc[i][j][3] + bvv);
          const size_t addr = (((size_t)z * 4 + (rb >> 10)) * 768 + cc) * 1024 + (rb & 1023);
          *(short4*)&p.C2[addr] = pk;
        }
      }
    } else if constexpr (MODE == 4) {
#pragma unroll
      for (int i = 0; i < 4; i++) {
        const int rb = m0 + wm + i * 16 + quad * 4;
#pragma unroll
        for (int r = 0; r < 4; r++)
          p.Cf[(size_t)z * p.c_zs + (size_t)(rb + r) * p.ldc + col] = acc[i][j][r];
      }
    } else {  // MODE 3: gelu, tanh form: t*sigmoid(1.59577*t*(1+0.044715*t^2))
              // max |err| < 5e-4 vs exact erf-gelu; ~1 v_exp vs branchy libm erff
      const float bvv = p.bias0[col];
#pragma unroll
      for (int i = 0; i < 4; i++) {
        const int rb = m0 + wm + i * 16 + quad * 4;
#pragma unroll
        for (int r = 0; r < 4; r++) {
          float t = acc[i][j][r] + bvv;
          float u = 1.59576912160573071176f * t * (1.0f + 0.044715f * t * t);
          float gl = __fdividef(t, 1.0f + __expf(-u));
          p.C0[(size_t)(rb + r) * p.ldc + col] = f2b(gl);
        }
      }
    }
  }
}

__global__ void __launch_bounds__(256) gemm_qkv(GP p)   { gemm_body<5, 0>(p); }
__global__ void __launch_bounds__(256) gemm_sco(GP p)   { gemm_body<0, 1>(p); }
__global__ void __launch_bounds__(256) gemm_pv(GP p)    { gemm_body<0, 2>(p); }
__global__ void __launch_bounds__(256) gemm_cproj(GP p) { gemm_body<4, 0>(p); }
__global__ void __launch_bounds__(256) gemm_fc(GP p)    { gemm_body<3, 0>(p); }
__global__ void __launch_bounds__(256) gemm_mproj(GP p) { gemm_body<4, 0>(p); }

__global__ void __launch_bounds__(256) ln_kernel(
    const float* __restrict__ in, const float* __restrict__ g, const float* __restrict__ b,
    float* __restrict__ outf, short* __restrict__ outb)
{
  const long r = blockIdx.x;
  const float* x = in + r * 768;
  const int tid = threadIdx.x;
  float v0 = x[tid], v1 = x[tid + 256], v2 = x[tid + 512];
  float s = v0 + v1 + v2;
  float sq = v0 * v0 + v1 * v1 + v2 * v2;
  __shared__ float red[8];
  int lane = tid & 63, wave = tid >> 6;
#pragma unroll
  for (int o = 1; o < 64; o <<= 1) { s += __shfl_xor(s, o); sq += __shfl_xor(sq, o); }
  if (lane == 0) { red[wave] = s; red[4 + wave] = sq; }
  __syncthreads();
  s = red[0] + red[1] + red[2] + red[3];
  sq = red[4] + red[5] + red[6] + red[7];
  float mean = s * (1.0f / 768.0f);
  float var = sq * (1.0f / 768.0f) - mean * mean;
  float inv = rsqrtf(var + 1e-5f);
#pragma unroll
  for (int u = 0; u < 3; u++) {
    int c = tid + u * 256;
    float v = (u == 0) ? v0 : ((u == 1) ? v1 : v2);
    float y = (v - mean) * inv * g[c] + b[c];
    outf[r * 768 + c] = y;
    outb[r * 768 + c] = f2b(y);
  }
}

// y = sum(partials) + bias + resid; then LayerNorm(y)*g+b -> outf (fp32) + outb (bf16).
__global__ void __launch_bounds__(256) reduce_ln_kernel(
    const float* __restrict__ part, long pzs, int nsplit,
    const float* __restrict__ bias, const float* __restrict__ resid,
    const float* __restrict__ g, const float* __restrict__ b,
    float* __restrict__ outf, short* __restrict__ outb)
{
  const long r = blockIdx.x;
  const int tid = threadIdx.x;
  float y[3];
#pragma unroll
  for (int u = 0; u < 3; u++) {
    const int c = tid + u * 256;
    const size_t idx = (size_t)r * 768 + c;
    float s = part[idx];
    for (int zz = 1; zz < nsplit; zz++) s += part[(size_t)zz * pzs + idx];
    y[u] = s + bias[c] + resid[idx];
  }
  float s = y[0] + y[1] + y[2];
  float sq = y[0] * y[0] + y[1] * y[1] + y[2] * y[2];
  __shared__ float red[8];
  int lane = tid & 63, wave = tid >> 6;
#pragma unroll
  for (int o = 1; o < 64; o <<= 1) { s += __shfl_xor(s, o); sq += __shfl_xor(sq, o); }
  if (lane == 0) { red[wave] = s; red[4 + wave] = sq; }
  __syncthreads();
  s = red[0] + red[1] + red[2] + red[3];
  sq = red[4] + red[5] + red[6] + red[7];
  float mean = s * (1.0f / 768.0f);
  float var = sq * (1.0f / 768.0f) - mean * mean;
  float inv = rsqrtf(var + 1e-5f);
#pragma unroll
  for (int u = 0; u < 3; u++) {
    const int c = tid + u * 256;
    const float v = (y[u] - mean) * inv * g[c] + b[c];
    outf[(size_t)r * 768 + c] = v;
    outb[(size_t)r * 768 + c] = f2b(v);
  }
}

__global__ void __launch_bounds__(256) softmax_kernel(short* __restrict__ sc)
{
  const long gr = blockIdx.x;
  const int i = (int)(gr & 1023);
  short* row = sc + (gr >> 10) * (1024L * 1024) + (long)i * 1024;
  const int L = i + 1;
  const int tid = threadIdx.x;
  const int lane = tid & 63, wave = tid >> 6;
  __shared__ float red[4];
  float v[4];
  float mx = -3.0e38f;
#pragma unroll
  for (int s = 0; s < 4; s++) {
    int j = tid + s * 256;
    v[s] = (j < L) ? b2f(row[j]) : -3.0e38f;
    mx = fmaxf(mx, v[s]);
  }
#pragma unroll
  for (int o = 1; o < 64; o <<= 1) mx = fmaxf(mx, __shfl_xor(mx, o));
  if (lane == 0) red[wave] = mx;
  __syncthreads();
  mx = fmaxf(fmaxf(red[0], red[1]), fmaxf(red[2], red[3]));
  __syncthreads();
  float sum = 0.0f;
#pragma unroll
  for (int s = 0; s < 4; s++) {
    int j = tid + s * 256;
    if (j < L) { v[s] = __expf(v[s] - mx); sum += v[s]; }
  }
#pragma unroll
  for (int o = 1; o < 64; o <<= 1) sum += __shfl_xor(sum, o);
  if (lane == 0) red[wave] = sum;
  __syncthreads();
  sum = red[0] + red[1] + red[2] + red[3];
  float inv = 1.0f / sum;
#pragma unroll
  for (int s = 0; s < 4; s++) {
    int j = tid + s * 256;
    if (j < L) row[j] = f2b(v[s] * inv);
  }
  const int hi = i | 127;
  for (int j = L + tid; j <= hi; j += 256) row[j] = 0;
}

__global__ void __launch_bounds__(256) reduce_kernel(
    const float* __restrict__ part, long pzs, int nsplit,
    const float* __restrict__ bias, const float* __restrict__ resid,
    float* __restrict__ out)
{
  const size_t idx = ((size_t)blockIdx.x * 256 + threadIdx.x) * 4;
  float4 s = *(const float4*)&part[idx];
  for (int zz = 1; zz < nsplit; zz++) {
    float4 q = *(const float4*)&part[(size_t)zz * pzs + idx];
    s.x += q.x; s.y += q.y; s.z += q.z; s.w += q.w;
  }
  const int c = (int)(idx % 768);
  float4 b = *(const float4*)&bias[c];
  float4 r = *(const float4*)&resid[idx];
  *(float4*)&out[idx] = make_float4(s.x + b.x + r.x, s.y + b.y + r.y,
                                    s.z + b.z + r.z, s.w + b.w + r.w);
}

// W[R][C] fp32 -> Wt[C][R] bf16, per-z src/dst strides
__global__ void __launch_bounds__(256) transpose_kernel(
    const float* __restrict__ W, short* __restrict__ Wt, int R, int C, long szs, long dzs)
{
  __shared__ float tile[32][33];
  const int c0 = blockIdx.x * 32, r0 = blockIdx.y * 32;
  const float* Wz = W + (size_t)blockIdx.z * szs;
  short* Wtz = Wt + (size_t)blockIdx.z * dzs;
  const int tx = threadIdx.x, ty = threadIdx.y;
#pragma unroll
  for (int i = 0; i < 32; i += 8)
    tile[ty + i][tx] = Wz[(size_t)(r0 + ty + i) * C + (c0 + tx)];
  __syncthreads();
#pragma unroll
  for (int i = 0; i < 32; i += 8)
    Wtz[(size_t)(c0 + ty + i) * R + (r0 + tx)] = f2b(tile[tx][ty + i]);
}

extern "C" void kernel_launch(void* const* d_in, const int* in_sizes, int n_in,
                              void* d_out, int out_size, void* d_ws, size_t ws_size,
                              hipStream_t stream)
{
  (void)in_sizes; (void)n_in; (void)out_size;
  const float* inputs = (const float*)d_in[0];
  const float* g1  = (const float*)d_in[1];
  const float* b1  = (const float*)d_in[2];
  const float* Wq  = (const float*)d_in[3];
  const float* bq  = (const float*)d_in[4];
  const float* Wk  = (const float*)d_in[5];
  const float* bk  = (const float*)d_in[6];
  const float* Wv  = (const float*)d_in[7];
  const float* bv  = (const float*)d_in[8];
  const float* Wc  = (const float*)d_in[9];
  const float* bc  = (const float*)d_in[10];
  const float* g2  = (const float*)d_in[11];
  const float* b2  = (const float*)d_in[12];
  const float* Wfc = (const float*)d_in[13];
  const float* bfc = (const float*)d_in[14];
  const float* Wp  = (const float*)d_in[15];
  const float* bp  = (const float*)d_in[16];
  float* out = (float*)d_out;

  const size_t NS = 4096, E = 768, S = 1024;

  char* base = (char*)d_ws;
  size_t off = 0;
  auto alloc = [&](size_t n) { char* r = base + off; off = (off + n + 255) & ~(size_t)255; return r; };

  // ---- persistent region (live across whole launch) ----
  float* x_f  = (float*)alloc(NS * E * 4);
  short* x_b  = (short*)alloc(NS * E * 2);
  short* Wqkv = (short*)alloc(12 * 3 * E * E * 2);   // [h][{q,k,v}][768][768] bf16 (B^T)
  short* WcT  = (short*)alloc(E * 9216 * 2);
  short* WfcT = (short*)alloc(3072 * E * 2);
  short* WpT  = (short*)alloc(E * 3072 * 2);
  short* cat  = (short*)alloc(12 * NS * E * 2);      // head-major [h][4096][768]; aliases partB later

  // ---- overlay region R: attention pool, then post-attention buffers ----
  char* Rp = base + off;
  const size_t R_size = (ws_size > off) ? (ws_size - off) : 0;

  const size_t per_h = 3 * (NS * E * 2) + 4 * S * S * 2;
  static const int Gs[5] = {6, 4, 3, 2, 1};
  int G = 1;
  for (int i = 0; i < 5; i++)
    if ((size_t)Gs[i] * per_h <= R_size) { G = Gs[i]; break; }

  short* q_g  = (short*)Rp;
  short* k_g  = q_g + (size_t)G * NS * E;
  short* vT_g = k_g + (size_t)G * NS * E;            // [z*4+n][768][1024]
  short* sc_g = vT_g + (size_t)G * NS * E;           // [z*4+n][1024][1024]

  // post-attention overlay (attention pool dead by then)
  size_t o2 = 0;
  float* partA = (float*)(Rp + o2); o2 += 4 * NS * E * 4;   // c_proj split-K=4 partials
  float* y2_f  = (float*)(Rp + o2); o2 += NS * E * 4;
  short* y2_b  = (short*)(Rp + o2); o2 += NS * E * 2;
  short* h_b   = (short*)(Rp + o2); o2 += NS * 3072 * 2;
  float* partB = (float*)cat;                               // 50.3 MB <= cat (75.5 MB)

  const dim3 tb(32, 8);
  transpose_kernel<<<dim3(24, 24, 12), tb, 0, stream>>>(Wq, Wqkv,         768, 768, (long)(E*E), (long)(3*E*E));
  transpose_kernel<<<dim3(24, 24, 12), tb, 0, stream>>>(Wk, Wqkv + E*E,   768, 768, (long)(E*E), (long)(3*E*E));
  transpose_kernel<<<dim3(24, 24, 12), tb, 0, stream>>>(Wv, Wqkv + 2*E*E, 768, 768, (long)(E*E), (long)(3*E*E));
  transpose_kernel<<<dim3(24, 288, 1), tb, 0, stream>>>(Wc, WcT, 9216, 768, 0, 0);
  transpose_kernel<<<dim3(96, 24, 1),  tb, 0, stream>>>(Wfc, WfcT, 768, 3072, 0, 0);
  transpose_kernel<<<dim3(24, 96, 1),  tb, 0, stream>>>(Wp, WpT, 3072, 768, 0, 0);

  ln_kernel<<<4096, 256, 0, stream>>>(inputs, g1, b1, x_f, x_b);

  const float sca = 0.03608439182435161f;  // 1/sqrt(768)
  for (int h0 = 0; h0 < 12; h0 += G) {
    {  // merged QKV: N = 2304 per head; grid.x = m (32, XCD-aligned)
      GP p{};
      p.A = x_b; p.lda = 768; p.a_bs = 0;
      p.B = Wqkv + (size_t)h0 * 3 * E * E; p.ldb = 768; p.b_bs = (long)(3 * E * E);
      p.bias0 = bq; p.bias1 = bk; p.bias2 = bv; p.zoff = h0;
      p.C0 = q_g; p.C1 = k_g; p.C2 = vT_g; p.c_zs = (long)(NS * E);
      p.ldc = 768; p.zmod = 1;
      p.K = 768; p.alpha = 1.0f;
      gemm_qkv<<<dim3(32, 18, G), 256, 0, stream>>>(p);
    }
    {  // scores = q k^T / sqrt(E)
      GP p{};
      p.A = q_g; p.lda = 768; p.a_bs = (long)(S * E);
      p.B = k_g; p.ldb = 768; p.b_bs = (long)(S * E);
      p.C0 = sc_g; p.ldc = 1024; p.zmod = 1; p.cz0 = 0; p.cz1 = (long)(S * S);
      p.K = 768; p.alpha = sca;
      gemm_sco<<<dim3(8, 8, 4 * G), 256, 0, stream>>>(p);
    }
    softmax_kernel<<<4 * G * 1024, 256, 0, stream>>>(sc_g);
    {  // heads = attn @ v -> cat[h][4096][768]
      GP p{};
      p.A = sc_g; p.lda = 1024; p.a_bs = (long)(S * S);
      p.B = vT_g; p.ldb = 1024; p.b_bs = (long)(E * S);
      p.C0 = cat + (size_t)h0 * NS * E; p.ldc = 768;
      p.zmod = 4; p.cz0 = (long)(S * E); p.cz1 = (long)(NS * E);
      p.K = 1024; p.alpha = 1.0f;
      gemm_pv<<<dim3(8, 6, 4 * G), 256, 0, stream>>>(p);
    }
  }

  {  // c_proj split-K=4 (kchunk = 2304 = 3 heads) over head-major cat
    GP p{};
    p.A = cat; p.lda = 768; p.a_kh = 768; p.a_hs = (long)(NS * E);
    p.B = WcT; p.ldb = 9216;
    p.Cf = partA; p.ldc = 768; p.c_zs = (long)(NS * E); p.zmod = 1;
    p.K = 9216; p.kchunk = 2304; p.alpha = 1.0f;
    gemm_cproj<<<dim3(32, 6, 4), 256, 0, stream>>>(p);
  }
  // y = sum(partA) + bc + x_f; y2 = LN(y)  (fused; y never materialized)
  reduce_ln_kernel<<<4096, 256, 0, stream>>>(partA, (long)(NS * E), 4, bc, x_f,
                                             g2, b2, y2_f, y2_b);

  {  // fc + tanh-form gelu
    GP p{};
    p.A = y2_b; p.lda = 768;
    p.B = WfcT; p.ldb = 768;
    p.bias0 = bfc; p.C0 = h_b; p.ldc = 3072; p.zmod = 1;
    p.K = 768; p.alpha = 1.0f;
    gemm_fc<<<dim3(32, 24, 1), 256, 0, stream>>>(p);
  }
  {  // proj split-K=4
    GP p{};
    p.A = h_b; p.lda = 3072;
    p.B = WpT; p.ldb = 3072;
    p.Cf = partB; p.ldc = 768; p.c_zs = (long)(NS * E); p.zmod = 1;
    p.K = 3072; p.kchunk = 768; p.alpha = 1.0f;
    gemm_mproj<<<dim3(32, 6, 4), 256, 0, stream>>>(p);
  }
  reduce_kernel<<<3072, 256, 0, stream>>>(partB, (long)(NS * E), 4, bp, y2_f, out);
}